// Round 5
// baseline (3570.710 us; speedup 1.0000x reference)
//
#include <hip/hip_runtime.h>
#include <hip/hip_bf16.h>

#define N_NODES 131072
#define N_GRAPHS 4096
#define D_Z 512
#define D_X 256
#define D_U 64
#define D_H 512
#define D_IN 768      // D_Z + D_X
#define KTOT 1280     // D_IN + D_H
#define NG1 1024      // two gates (Z,R) fused

using bf16   = __bf16;
using bf16x8 = __attribute__((ext_vector_type(8))) __bf16;
using f32x4  = __attribute__((ext_vector_type(4))) float;
using fl4    = __attribute__((ext_vector_type(4))) float;

__device__ __forceinline__ void gload_lds16(const void* g, void* lds) {
    __builtin_amdgcn_global_load_lds(
        (const __attribute__((address_space(1))) unsigned int*)g,
        (__attribute__((address_space(3))) unsigned int*)lds,
        16, 0, 0);
}

// ---------------- prep: weights -> bf16, transposed WT[n][k]; fused biases ---
__global__ void prep_weights(const float* __restrict__ Wxz, const float* __restrict__ Whz,
                             const float* __restrict__ Wxr, const float* __restrict__ Whr,
                             const float* __restrict__ Wxh, const float* __restrict__ Whh,
                             const float* __restrict__ bxz, const float* __restrict__ bhz,
                             const float* __restrict__ bxr, const float* __restrict__ bhr,
                             const float* __restrict__ bxh, const float* __restrict__ bhh,
                             bf16* __restrict__ WT1, bf16* __restrict__ WT2,
                             float* __restrict__ bias1, float* __restrict__ bias2)
{
    int idx = blockIdx.x * blockDim.x + threadIdx.x;
    if (idx < NG1)
        bias1[idx] = (idx < D_H) ? (bxz[idx] + bhz[idx]) : (bxr[idx - D_H] + bhr[idx - D_H]);
    if (idx < D_H)
        bias2[idx] = bxh[idx] + bhh[idx];

    const int T1 = NG1 * (KTOT / 8);
    if (idx < T1) {
        int n = idx % NG1, kc = idx / NG1, k0 = kc * 8;
        int col = (n < D_H) ? n : n - D_H;
        const float* Wx = (n < D_H) ? Wxz : Wxr;
        const float* Wh = (n < D_H) ? Whz : Whr;
        bf16x8 o;
        #pragma unroll
        for (int i = 0; i < 8; ++i) {
            int k = k0 + i;
            float f = (k < D_IN) ? Wx[(long)k * D_H + col] : Wh[(long)(k - D_IN) * D_H + col];
            o[i] = (bf16)f;
        }
        *(bf16x8*)(WT1 + (long)n * KTOT + k0) = o;
    } else {
        int j = idx - T1;               // [0, 512*160)
        int n = j % D_H, kc = j / D_H, k0 = kc * 8;
        bf16x8 o;
        #pragma unroll
        for (int i = 0; i < 8; ++i) {
            int k = k0 + i;
            float f = (k < D_IN) ? Wxh[(long)k * D_H + n] : Whh[(long)(k - D_IN) * D_H + n];
            o[i] = (bf16)f;
        }
        *(bf16x8*)(WT2 + (long)n * KTOT + k0) = o;
    }
}

// ---------------- prep: A = [z | x | prev_h] -> bf16 [N_NODES][1280] ---------
__global__ void prep_A(const float* __restrict__ z, const float* __restrict__ x,
                       const float* __restrict__ ph, bf16* __restrict__ Abf)
{
    long idx = (long)blockIdx.x * blockDim.x + threadIdx.x;   // N_NODES*160
    long row = idx / 160;
    int  e   = (int)(idx % 160) * 8;
    const float* src;
    if (e < D_Z)        src = z  + row * D_Z + e;
    else if (e < D_IN)  src = x  + row * D_X + (e - D_Z);
    else                src = ph + row * D_H + (e - D_IN);
    fl4 v0 = *(const fl4*)src;
    fl4 v1 = *(const fl4*)(src + 4);
    bf16x8 o;
    o[0]=(bf16)v0[0]; o[1]=(bf16)v0[1]; o[2]=(bf16)v0[2]; o[3]=(bf16)v0[3];
    o[4]=(bf16)v1[0]; o[5]=(bf16)v1[1]; o[6]=(bf16)v1[2]; o[7]=(bf16)v1[3];
    *(bf16x8*)(Abf + row * KTOT + e) = o;
}

// ---------------- GEMM 128x128 tile, BK=64, 4 waves, single-buffer ----------
// R5 = R1's proven K-loop (implicit wave-overlap across >=4 blocks/CU is the
// m97/m114 mechanism) + R2's bijective XCD swizzle (FETCH ~ideal) + occupancy
// unlocked: 32 KB LDS only, __launch_bounds__(256,5) -> LDS-limited 5 blk/CU.
// MODE 1: C=[Z|R] gates -> sigmoid; Z (f32) -> Hout, Rapp=sigmoid*prev_h (bf16)
// MODE 2: C=H_tilde pre -> tanh; H = Z*prev_h + (1-Z)*H_tilde -> Hout
template<int NCOLS, int MODE>
__global__ __launch_bounds__(256, 5)
void gemm_kernel(const bf16* __restrict__ A,     // Abf [N][1280]
                 const bf16* __restrict__ A2,    // MODE2: Rapp [N][512] for k>=768
                 const bf16* __restrict__ W,     // WT [NCOLS][1280]
                 const float* __restrict__ bias, // [NCOLS]
                 const float* __restrict__ prev_h,
                 float* __restrict__ Hout,
                 bf16* __restrict__ Rapp_out)
{
    __shared__ __align__(16) char Atile[16384];  // [128 rows][64 k] bf16, swizzled
    __shared__ __align__(16) char Btile[16384];  // [128 cols][64 k] bf16, swizzled

    const int tid = threadIdx.x;
    const int w = tid >> 6, l = tid & 63;

    // T1: bijective XCD swizzle (nwg % 8 == 0 for both instantiations)
    constexpr int nb  = NCOLS / 128;
    constexpr int nwg = (N_NODES / 128) * nb;
    constexpr int cpx = nwg / 8;
    const int bid = blockIdx.x;
    const int swz = (bid & 7) * cpx + (bid >> 3);
    const int  bn = swz % nb;
    const long m0 = (long)(swz / nb) * 128;
    const int  n0 = bn * 128;

    // staging: per round r, this thread fills linear LDS o = r*4096 + w*1024 + l*16
    const int chunkl = l >> 3;                           // == srow&7
    const int kes    = (((l & 7) * 16) ^ (chunkl << 4)) >> 1;  // pre-swizzled src elem

    f32x4 acc[4][4];
    #pragma unroll
    for (int i = 0; i < 4; ++i)
        #pragma unroll
        for (int j = 0; j < 4; ++j) acc[i][j] = f32x4{0.f, 0.f, 0.f, 0.f};

    const int wr = w >> 1, wc = w & 1;
    const int lr = l & 15, lg = l >> 4;

    for (int k0 = 0; k0 < KTOT; k0 += 64) {
        __syncthreads();
        const bf16* Asrc; long astr; int kofs;
        if (MODE == 2 && k0 >= D_IN) { Asrc = A2; astr = D_H;  kofs = k0 - D_IN; }
        else                         { Asrc = A;  astr = KTOT; kofs = k0; }
        #pragma unroll
        for (int r = 0; r < 4; ++r) {
            int srow = (r * 4 + w) * 8 + chunkl;
            gload_lds16(Asrc + (m0 + srow) * astr + kofs + kes,
                        Atile + r * 4096 + w * 1024);
            gload_lds16(W + (long)(n0 + srow) * KTOT + k0 + kes,
                        Btile + r * 4096 + w * 1024);
        }
        __syncthreads();   // compiler drains vmcnt before s_barrier

        #pragma unroll
        for (int ks = 0; ks < 2; ++ks) {
            bf16x8 af[4], bfr[4];
            #pragma unroll
            for (int mi = 0; mi < 4; ++mi) {
                int row = wr * 64 + mi * 16 + lr;
                int addr = (row << 7) + ks * 64 + lg * 16;
                addr ^= (row & 7) << 4;
                af[mi] = *(const bf16x8*)(Atile + addr);
            }
            #pragma unroll
            for (int ni = 0; ni < 4; ++ni) {
                int row = wc * 64 + ni * 16 + lr;
                int addr = (row << 7) + ks * 64 + lg * 16;
                addr ^= (row & 7) << 4;
                bfr[ni] = *(const bf16x8*)(Btile + addr);
            }
            #pragma unroll
            for (int mi = 0; mi < 4; ++mi)
                #pragma unroll
                for (int ni = 0; ni < 4; ++ni)
                    acc[mi][ni] = __builtin_amdgcn_mfma_f32_16x16x32_bf16(
                        af[mi], bfr[ni], acc[mi][ni], 0, 0, 0);
        }
    }

    // epilogue: C/D layout col = lane&15, row = (lane>>4)*4 + j   [m89 verified]
    #pragma unroll
    for (int mi = 0; mi < 4; ++mi) {
        #pragma unroll
        for (int ni = 0; ni < 4; ++ni) {
            int gc = n0 + wc * 64 + ni * 16 + lr;
            float bv = bias[gc];
            #pragma unroll
            for (int j = 0; j < 4; ++j) {
                long gr = m0 + wr * 64 + mi * 16 + lg * 4 + j;
                float v = acc[mi][ni][j] + bv;
                if (MODE == 1) {
                    float s = 1.f / (1.f + __expf(-v));
                    if (gc < D_H) {
                        Hout[gr * D_H + gc] = s;                    // Z in f32
                    } else {
                        float ph = prev_h[gr * D_H + (gc - D_H)];
                        Rapp_out[gr * D_H + (gc - D_H)] = (bf16)(s * ph);
                    }
                } else {
                    float ht = 2.f / (1.f + __expf(-2.f * v)) - 1.f;   // tanh
                    long  o  = gr * D_H + gc;
                    float zz = Hout[o];
                    float ph = prev_h[o];
                    Hout[o] = zz * ph + (1.f - zz) * ht;
                }
            }
        }
    }
}

// ---------------- fusion: segment_sum(z) | relu(u@Wg+bg) per graph ----------
__global__ __launch_bounds__(256)
void fusion_kernel(const float* __restrict__ z, const float* __restrict__ u,
                   const float* __restrict__ Wg, const float* __restrict__ bg,
                   const int* __restrict__ batch, float* __restrict__ out)
{
    int g = blockIdx.x;
    __shared__ float us[D_U];
    __shared__ int   rng[2];
    int tid = threadIdx.x;
    if (tid < D_U) us[tid] = u[(long)g * D_U + tid];
    if (tid < 2) {
        int target = g + tid;     // lower_bound(batch, target)
        int lo = 0, hi = N_NODES;
        while (lo < hi) { int mid = (lo + hi) >> 1; if (batch[mid] < target) lo = mid + 1; else hi = mid; }
        rng[tid] = lo;
    }
    __syncthreads();
    int start = rng[0], end = rng[1];
    int d0 = tid * 2;
    float s0 = 0.f, s1 = 0.f;
    for (int n = start; n < end; ++n) {
        const float* zp = z + (long)n * D_Z + d0;
        s0 += zp[0]; s1 += zp[1];
    }
    long ob = (long)g * 1024;
    out[ob + d0]     = s0;
    out[ob + d0 + 1] = s1;
    float a0 = bg[d0], a1 = bg[d0 + 1];
    #pragma unroll 8
    for (int k = 0; k < D_U; ++k) {
        float uv = us[k];
        a0 += uv * Wg[k * D_Z + d0];
        a1 += uv * Wg[k * D_Z + d0 + 1];
    }
    out[ob + 512 + d0]     = fmaxf(a0, 0.f);
    out[ob + 512 + d0 + 1] = fmaxf(a1, 0.f);
}

// ---------------------------------------------------------------------------
extern "C" void kernel_launch(void* const* d_in, const int* in_sizes, int n_in,
                              void* d_out, int out_size, void* d_ws, size_t ws_size,
                              hipStream_t stream) {
    (void)in_sizes; (void)n_in; (void)out_size; (void)ws_size;
    const float* z      = (const float*)d_in[0];
    const float* u      = (const float*)d_in[1];
    const float* x      = (const float*)d_in[2];
    const float* prev_h = (const float*)d_in[3];
    // d_in[4] edge_index unused (K=1 ChebConv)
    const int*   batch  = (const int*)d_in[5];
    // d_in[6] batch_size == 4096 (fixed)
    const float* Wxz = (const float*)d_in[7];
    const float* bxz = (const float*)d_in[8];
    const float* Whz = (const float*)d_in[9];
    const float* bhz = (const float*)d_in[10];
    const float* Wxr = (const float*)d_in[11];
    const float* bxr = (const float*)d_in[12];
    const float* Whr = (const float*)d_in[13];
    const float* bhr = (const float*)d_in[14];
    const float* Wxh = (const float*)d_in[15];
    const float* bxh = (const float*)d_in[16];
    const float* Whh = (const float*)d_in[17];
    const float* bhh = (const float*)d_in[18];
    const float* Wg  = (const float*)d_in[19];
    const float* bg  = (const float*)d_in[20];

    char* ws = (char*)d_ws;
    bf16*  WT1   = (bf16*)ws;                                  // 2,621,440 B
    bf16*  WT2   = (bf16*)(ws + 2621440);                      // 1,310,720 B
    float* bias1 = (float*)(ws + 3932160);                     // 4 KB
    float* bias2 = (float*)(ws + 3936256);                     // 2 KB
    bf16*  Rapp  = (bf16*)(ws + 4194304);                      // 134,217,728 B
    bf16*  Abf   = (bf16*)(ws + 4194304 + 134217728);          // 335,544,320 B

    float* outF = (float*)d_out;
    float* Hout = outF + (long)N_GRAPHS * 1024;                // H region (also Z staging)

    hipLaunchKernelGGL(prep_weights, dim3(960), dim3(256), 0, stream,
                       Wxz, Whz, Wxr, Whr, Wxh, Whh,
                       bxz, bhz, bxr, bhr, bxh, bhh,
                       WT1, WT2, bias1, bias2);
    hipLaunchKernelGGL(prep_A, dim3(81920), dim3(256), 0, stream, z, x, prev_h, Abf);
    hipLaunchKernelGGL((gemm_kernel<NG1, 1>), dim3(8192), dim3(256), 0, stream,
                       Abf, (const bf16*)nullptr, WT1, bias1, prev_h, Hout, Rapp);
    hipLaunchKernelGGL((gemm_kernel<D_H, 2>), dim3(4096), dim3(256), 0, stream,
                       Abf, Rapp, WT2, bias2, prev_h, Hout, (bf16*)nullptr);
    hipLaunchKernelGGL(fusion_kernel, dim3(N_GRAPHS), dim3(256), 0, stream,
                       z, u, Wg, bg, batch, outF);
}

// Round 6
// 1297.198 us; speedup vs baseline: 2.7526x; 2.7526x over previous
//
#include <hip/hip_runtime.h>
#include <hip/hip_bf16.h>

#define N_NODES 131072
#define N_GRAPHS 4096
#define D_Z 512
#define D_X 256
#define D_U 64
#define D_H 512
#define D_IN 768      // D_Z + D_X
#define KTOT 1280     // D_IN + D_H
#define NG1 1024      // two gates (Z,R) fused

using bf16   = __bf16;
using bf16x8 = __attribute__((ext_vector_type(8))) __bf16;
using f32x4  = __attribute__((ext_vector_type(4))) float;
using fl4    = __attribute__((ext_vector_type(4))) float;

__device__ __forceinline__ void gload_lds16(const void* g, void* lds) {
    __builtin_amdgcn_global_load_lds(
        (const __attribute__((address_space(1))) unsigned int*)g,
        (__attribute__((address_space(3))) unsigned int*)lds,
        16, 0, 0);
}

// ---------------- prep: weights -> bf16, transposed WT[n][k]; fused biases ---
__global__ void prep_weights(const float* __restrict__ Wxz, const float* __restrict__ Whz,
                             const float* __restrict__ Wxr, const float* __restrict__ Whr,
                             const float* __restrict__ Wxh, const float* __restrict__ Whh,
                             const float* __restrict__ bxz, const float* __restrict__ bhz,
                             const float* __restrict__ bxr, const float* __restrict__ bhr,
                             const float* __restrict__ bxh, const float* __restrict__ bhh,
                             bf16* __restrict__ WT1, bf16* __restrict__ WT2,
                             float* __restrict__ bias1, float* __restrict__ bias2)
{
    int idx = blockIdx.x * blockDim.x + threadIdx.x;
    if (idx < NG1)
        bias1[idx] = (idx < D_H) ? (bxz[idx] + bhz[idx]) : (bxr[idx - D_H] + bhr[idx - D_H]);
    if (idx < D_H)
        bias2[idx] = bxh[idx] + bhh[idx];

    const int T1 = NG1 * (KTOT / 8);
    if (idx < T1) {
        int n = idx % NG1, kc = idx / NG1, k0 = kc * 8;
        int col = (n < D_H) ? n : n - D_H;
        const float* Wx = (n < D_H) ? Wxz : Wxr;
        const float* Wh = (n < D_H) ? Whz : Whr;
        bf16x8 o;
        #pragma unroll
        for (int i = 0; i < 8; ++i) {
            int k = k0 + i;
            float f = (k < D_IN) ? Wx[(long)k * D_H + col] : Wh[(long)(k - D_IN) * D_H + col];
            o[i] = (bf16)f;
        }
        *(bf16x8*)(WT1 + (long)n * KTOT + k0) = o;
    } else {
        int j = idx - T1;               // [0, 512*160)
        int n = j % D_H, kc = j / D_H, k0 = kc * 8;
        bf16x8 o;
        #pragma unroll
        for (int i = 0; i < 8; ++i) {
            int k = k0 + i;
            float f = (k < D_IN) ? Wxh[(long)k * D_H + n] : Whh[(long)(k - D_IN) * D_H + n];
            o[i] = (bf16)f;
        }
        *(bf16x8*)(WT2 + (long)n * KTOT + k0) = o;
    }
}

// ---------------- prep: A = [z | x | prev_h] -> bf16 [N_NODES][1280] ---------
__global__ void prep_A(const float* __restrict__ z, const float* __restrict__ x,
                       const float* __restrict__ ph, bf16* __restrict__ Abf)
{
    long idx = (long)blockIdx.x * blockDim.x + threadIdx.x;   // N_NODES*160
    long row = idx / 160;
    int  e   = (int)(idx % 160) * 8;
    const float* src;
    if (e < D_Z)        src = z  + row * D_Z + e;
    else if (e < D_IN)  src = x  + row * D_X + (e - D_Z);
    else                src = ph + row * D_H + (e - D_IN);
    fl4 v0 = *(const fl4*)src;
    fl4 v1 = *(const fl4*)(src + 4);
    bf16x8 o;
    o[0]=(bf16)v0[0]; o[1]=(bf16)v0[1]; o[2]=(bf16)v0[2]; o[3]=(bf16)v0[3];
    o[4]=(bf16)v1[0]; o[5]=(bf16)v1[1]; o[6]=(bf16)v1[2]; o[7]=(bf16)v1[3];
    *(bf16x8*)(Abf + row * KTOT + e) = o;
}

// ---------------- GEMM 128x64 tile, BK=64, 4 waves (2x2), single-buffer -----
// R6: occupancy via SMALLER PER-WAVE TILE (wave-tile 64x32 -> acc 32 regs,
// total ~85 incl unified AGPR) instead of launch_bounds register squeeze
// (R5's spill disaster). LDS 24 KB/block -> target 5-6 blocks/CU.
// MODE 1: C=[Z|R] gates -> sigmoid; Z (f32) -> Hout, Rapp=sigmoid*prev_h (bf16)
// MODE 2: C=H_tilde pre -> tanh; H = Z*prev_h + (1-Z)*H_tilde -> Hout
template<int NCOLS, int MODE>
__global__ __launch_bounds__(256)
void gemm_kernel(const bf16* __restrict__ A,     // Abf [N][1280]
                 const bf16* __restrict__ A2,    // MODE2: Rapp [N][512] for k>=768
                 const bf16* __restrict__ W,     // WT [NCOLS][1280]
                 const float* __restrict__ bias, // [NCOLS]
                 const float* __restrict__ prev_h,
                 float* __restrict__ Hout,
                 bf16* __restrict__ Rapp_out)
{
    __shared__ __align__(16) char Atile[16384];  // [128 rows][64 k] bf16, swizzled
    __shared__ __align__(16) char Btile[8192];   // [ 64 cols][64 k] bf16, swizzled

    const int tid = threadIdx.x;
    const int w = tid >> 6, l = tid & 63;

    // T1: bijective XCD swizzle (nwg % 8 == 0 for both instantiations)
    constexpr int nb  = NCOLS / 64;
    constexpr int nwg = (N_NODES / 128) * nb;
    constexpr int cpx = nwg / 8;
    const int bid = blockIdx.x;
    const int swz = (bid & 7) * cpx + (bid >> 3);
    const int  bn = swz % nb;                    // n fastest -> A-tile L2 reuse
    const long m0 = (long)(swz / nb) * 128;
    const int  n0 = bn * 64;

    // staging: thread covers (row trow + r*32), granule tg; LDS dest linear
    // tid*16 per 4KB round; global col pre-swizzled so swizzled ds_read is ok.
    const int trow = tid >> 3;                   // 32 rows per round
    const int tg   = tid & 7;
    const int kes  = ((tg * 16) ^ ((trow & 7) << 4)) >> 1;   // (row&7)==(trow&7)

    f32x4 acc[4][2];
    #pragma unroll
    for (int i = 0; i < 4; ++i)
        #pragma unroll
        for (int j = 0; j < 2; ++j) acc[i][j] = f32x4{0.f, 0.f, 0.f, 0.f};

    const int wr = w >> 1, wc = w & 1;           // 2x2 wave grid
    const int lr = l & 15, lg = l >> 4;

    for (int k0 = 0; k0 < KTOT; k0 += 64) {
        __syncthreads();
        const bf16* Asrc; long astr; int kofs;
        if (MODE == 2 && k0 >= D_IN) { Asrc = A2; astr = D_H;  kofs = k0 - D_IN; }
        else                         { Asrc = A;  astr = KTOT; kofs = k0; }
        #pragma unroll
        for (int r = 0; r < 4; ++r)              // A: 128 rows, 4 rounds
            gload_lds16(Asrc + (m0 + r * 32 + trow) * astr + kofs + kes,
                        Atile + r * 4096 + tid * 16);
        #pragma unroll
        for (int r = 0; r < 2; ++r)              // B: 64 cols, 2 rounds
            gload_lds16(W + (long)(n0 + r * 32 + trow) * KTOT + k0 + kes,
                        Btile + r * 4096 + tid * 16);
        __syncthreads();   // compiler drains vmcnt before s_barrier

        #pragma unroll
        for (int ks = 0; ks < 2; ++ks) {
            bf16x8 af[4], bfr[2];
            #pragma unroll
            for (int mi = 0; mi < 4; ++mi) {
                int row = wr * 64 + mi * 16 + lr;
                int addr = (row << 7) + ((ks * 64 + lg * 16) ^ ((row & 7) << 4));
                af[mi] = *(const bf16x8*)(Atile + addr);
            }
            #pragma unroll
            for (int ni = 0; ni < 2; ++ni) {
                int row = wc * 32 + ni * 16 + lr;
                int addr = (row << 7) + ((ks * 64 + lg * 16) ^ ((row & 7) << 4));
                bfr[ni] = *(const bf16x8*)(Btile + addr);
            }
            #pragma unroll
            for (int mi = 0; mi < 4; ++mi)
                #pragma unroll
                for (int ni = 0; ni < 2; ++ni)
                    acc[mi][ni] = __builtin_amdgcn_mfma_f32_16x16x32_bf16(
                        af[mi], bfr[ni], acc[mi][ni], 0, 0, 0);
        }
    }

    // epilogue: C/D layout col = lane&15, row = (lane>>4)*4 + j   [m89 verified]
    #pragma unroll
    for (int mi = 0; mi < 4; ++mi) {
        #pragma unroll
        for (int ni = 0; ni < 2; ++ni) {
            int gc = n0 + wc * 32 + ni * 16 + lr;
            float bv = bias[gc];
            #pragma unroll
            for (int j = 0; j < 4; ++j) {
                long gr = m0 + wr * 64 + mi * 16 + lg * 4 + j;
                float v = acc[mi][ni][j] + bv;
                if (MODE == 1) {
                    float s = 1.f / (1.f + __expf(-v));
                    if (gc < D_H) {
                        Hout[gr * D_H + gc] = s;                    // Z in f32
                    } else {
                        float ph = prev_h[gr * D_H + (gc - D_H)];
                        Rapp_out[gr * D_H + (gc - D_H)] = (bf16)(s * ph);
                    }
                } else {
                    float ht = 2.f / (1.f + __expf(-2.f * v)) - 1.f;   // tanh
                    long  o  = gr * D_H + gc;
                    float zz = Hout[o];
                    float ph = prev_h[o];
                    Hout[o] = zz * ph + (1.f - zz) * ht;
                }
            }
        }
    }
}

// ---------------- fusion: segment_sum(z) | relu(u@Wg+bg) per graph ----------
__global__ __launch_bounds__(256)
void fusion_kernel(const float* __restrict__ z, const float* __restrict__ u,
                   const float* __restrict__ Wg, const float* __restrict__ bg,
                   const int* __restrict__ batch, float* __restrict__ out)
{
    int g = blockIdx.x;
    __shared__ float us[D_U];
    __shared__ int   rng[2];
    int tid = threadIdx.x;
    if (tid < D_U) us[tid] = u[(long)g * D_U + tid];
    if (tid < 2) {
        int target = g + tid;     // lower_bound(batch, target)
        int lo = 0, hi = N_NODES;
        while (lo < hi) { int mid = (lo + hi) >> 1; if (batch[mid] < target) lo = mid + 1; else hi = mid; }
        rng[tid] = lo;
    }
    __syncthreads();
    int start = rng[0], end = rng[1];
    int d0 = tid * 2;
    float s0 = 0.f, s1 = 0.f;
    for (int n = start; n < end; ++n) {
        const float* zp = z + (long)n * D_Z + d0;
        s0 += zp[0]; s1 += zp[1];
    }
    long ob = (long)g * 1024;
    out[ob + d0]     = s0;
    out[ob + d0 + 1] = s1;
    float a0 = bg[d0], a1 = bg[d0 + 1];
    #pragma unroll 8
    for (int k = 0; k < D_U; ++k) {
        float uv = us[k];
        a0 += uv * Wg[k * D_Z + d0];
        a1 += uv * Wg[k * D_Z + d0 + 1];
    }
    out[ob + 512 + d0]     = fmaxf(a0, 0.f);
    out[ob + 512 + d0 + 1] = fmaxf(a1, 0.f);
}

// ---------------------------------------------------------------------------
extern "C" void kernel_launch(void* const* d_in, const int* in_sizes, int n_in,
                              void* d_out, int out_size, void* d_ws, size_t ws_size,
                              hipStream_t stream) {
    (void)in_sizes; (void)n_in; (void)out_size; (void)ws_size;
    const float* z      = (const float*)d_in[0];
    const float* u      = (const float*)d_in[1];
    const float* x      = (const float*)d_in[2];
    const float* prev_h = (const float*)d_in[3];
    // d_in[4] edge_index unused (K=1 ChebConv)
    const int*   batch  = (const int*)d_in[5];
    // d_in[6] batch_size == 4096 (fixed)
    const float* Wxz = (const float*)d_in[7];
    const float* bxz = (const float*)d_in[8];
    const float* Whz = (const float*)d_in[9];
    const float* bhz = (const float*)d_in[10];
    const float* Wxr = (const float*)d_in[11];
    const float* bxr = (const float*)d_in[12];
    const float* Whr = (const float*)d_in[13];
    const float* bhr = (const float*)d_in[14];
    const float* Wxh = (const float*)d_in[15];
    const float* bxh = (const float*)d_in[16];
    const float* Whh = (const float*)d_in[17];
    const float* bhh = (const float*)d_in[18];
    const float* Wg  = (const float*)d_in[19];
    const float* bg  = (const float*)d_in[20];

    char* ws = (char*)d_ws;
    bf16*  WT1   = (bf16*)ws;                                  // 2,621,440 B
    bf16*  WT2   = (bf16*)(ws + 2621440);                      // 1,310,720 B
    float* bias1 = (float*)(ws + 3932160);                     // 4 KB
    float* bias2 = (float*)(ws + 3936256);                     // 2 KB
    bf16*  Rapp  = (bf16*)(ws + 4194304);                      // 134,217,728 B
    bf16*  Abf   = (bf16*)(ws + 4194304 + 134217728);          // 335,544,320 B

    float* outF = (float*)d_out;
    float* Hout = outF + (long)N_GRAPHS * 1024;                // H region (also Z staging)

    hipLaunchKernelGGL(prep_weights, dim3(960), dim3(256), 0, stream,
                       Wxz, Whz, Wxr, Whr, Wxh, Whh,
                       bxz, bhz, bxr, bhr, bxh, bhh,
                       WT1, WT2, bias1, bias2);
    hipLaunchKernelGGL(prep_A, dim3(81920), dim3(256), 0, stream, z, x, prev_h, Abf);
    hipLaunchKernelGGL((gemm_kernel<NG1, 1>), dim3(16384), dim3(256), 0, stream,
                       Abf, (const bf16*)nullptr, WT1, bias1, prev_h, Hout, Rapp);
    hipLaunchKernelGGL((gemm_kernel<D_H, 2>), dim3(8192), dim3(256), 0, stream,
                       Abf, Rapp, WT2, bias2, prev_h, Hout, (bf16*)nullptr);
    hipLaunchKernelGGL(fusion_kernel, dim3(N_GRAPHS), dim3(256), 0, stream,
                       z, u, Wg, bg, batch, outF);
}

// Round 7
// 1081.669 us; speedup vs baseline: 3.3011x; 1.1993x over previous
//
#include <hip/hip_runtime.h>
#include <hip/hip_bf16.h>

#define N_NODES 131072
#define N_GRAPHS 4096
#define D_Z 512
#define D_X 256
#define D_U 64
#define D_H 512
#define D_IN 768      // D_Z + D_X
#define KTOT 1280     // D_IN + D_H
#define NG1 1024      // two gates (Z,R) fused

using bf16   = __bf16;
using bf16x8 = __attribute__((ext_vector_type(8))) __bf16;
using f32x4  = __attribute__((ext_vector_type(4))) float;
using fl4    = __attribute__((ext_vector_type(4))) float;

__device__ __forceinline__ void gload_lds16(const void* g, void* lds) {
    __builtin_amdgcn_global_load_lds(
        (const __attribute__((address_space(1))) unsigned int*)g,
        (__attribute__((address_space(3))) unsigned int*)lds,
        16, 0, 0);
}

// ---------------- prep: weights -> bf16, transposed WT[n][k]; fused biases ---
__global__ void prep_weights(const float* __restrict__ Wxz, const float* __restrict__ Whz,
                             const float* __restrict__ Wxr, const float* __restrict__ Whr,
                             const float* __restrict__ Wxh, const float* __restrict__ Whh,
                             const float* __restrict__ bxz, const float* __restrict__ bhz,
                             const float* __restrict__ bxr, const float* __restrict__ bhr,
                             const float* __restrict__ bxh, const float* __restrict__ bhh,
                             bf16* __restrict__ WT1, bf16* __restrict__ WT2,
                             float* __restrict__ bias1, float* __restrict__ bias2)
{
    int idx = blockIdx.x * blockDim.x + threadIdx.x;
    if (idx < NG1)
        bias1[idx] = (idx < D_H) ? (bxz[idx] + bhz[idx]) : (bxr[idx - D_H] + bhr[idx - D_H]);
    if (idx < D_H)
        bias2[idx] = bxh[idx] + bhh[idx];

    const int T1 = NG1 * (KTOT / 8);
    if (idx < T1) {
        int n = idx % NG1, kc = idx / NG1, k0 = kc * 8;
        int col = (n < D_H) ? n : n - D_H;
        const float* Wx = (n < D_H) ? Wxz : Wxr;
        const float* Wh = (n < D_H) ? Whz : Whr;
        bf16x8 o;
        #pragma unroll
        for (int i = 0; i < 8; ++i) {
            int k = k0 + i;
            float f = (k < D_IN) ? Wx[(long)k * D_H + col] : Wh[(long)(k - D_IN) * D_H + col];
            o[i] = (bf16)f;
        }
        *(bf16x8*)(WT1 + (long)n * KTOT + k0) = o;
    } else {
        int j = idx - T1;               // [0, 512*160)
        int n = j % D_H, kc = j / D_H, k0 = kc * 8;
        bf16x8 o;
        #pragma unroll
        for (int i = 0; i < 8; ++i) {
            int k = k0 + i;
            float f = (k < D_IN) ? Wxh[(long)k * D_H + n] : Whh[(long)(k - D_IN) * D_H + n];
            o[i] = (bf16)f;
        }
        *(bf16x8*)(WT2 + (long)n * KTOT + k0) = o;
    }
}

// ---------------- prep: A = [z | x | prev_h] -> bf16 [N_NODES][1280] ---------
__global__ void prep_A(const float* __restrict__ z, const float* __restrict__ x,
                       const float* __restrict__ ph, bf16* __restrict__ Abf)
{
    long idx = (long)blockIdx.x * blockDim.x + threadIdx.x;   // N_NODES*160
    long row = idx / 160;
    int  e   = (int)(idx % 160) * 8;
    const float* src;
    if (e < D_Z)        src = z  + row * D_Z + e;
    else if (e < D_IN)  src = x  + row * D_X + (e - D_Z);
    else                src = ph + row * D_H + (e - D_IN);
    fl4 v0 = *(const fl4*)src;
    fl4 v1 = *(const fl4*)(src + 4);
    bf16x8 o;
    o[0]=(bf16)v0[0]; o[1]=(bf16)v0[1]; o[2]=(bf16)v0[2]; o[3]=(bf16)v0[3];
    o[4]=(bf16)v1[0]; o[5]=(bf16)v1[1]; o[6]=(bf16)v1[2]; o[7]=(bf16)v1[3];
    *(bf16x8*)(Abf + row * KTOT + e) = o;
}

// ------------- GEMM 128x128 tile, BK=64, 4 waves (2x2), single-buffer -------
// R7 = R6's occupancy mechanism + R1's MFMA:ds_read ratio. Wave-tile 64x64
// (acc 64 AGPR, 0.5 ds_read/MFMA); __launch_bounds__(256,4) -> 128-reg
// budget (acc 64 + ~56 VGPR fits; R5 failed because 102 < 64+minimum).
// Epilogues read prev_h as bf16 from Abf cols 768.. (saves 268 MB f32 reads).
// MODE 1: C=[Z|R] -> sigmoid; Z (f32) -> Hout staging, Rapp=sig*ph (bf16)
// MODE 2: C=H_tilde pre -> tanh; H = Z*ph + (1-Z)*Ht -> Hout
template<int NCOLS, int MODE>
__global__ __launch_bounds__(256, 4)
void gemm_kernel(const bf16* __restrict__ A,     // Abf [N][1280]
                 const bf16* __restrict__ A2,    // MODE2: Rapp [N][512] for k>=768
                 const bf16* __restrict__ W,     // WT [NCOLS][1280]
                 const float* __restrict__ bias, // [NCOLS]
                 float* __restrict__ Hout,
                 bf16* __restrict__ Rapp_out)
{
    __shared__ __align__(16) char Atile[16384];  // [128 rows][64 k] bf16, swizzled
    __shared__ __align__(16) char Btile[16384];  // [128 cols][64 k] bf16, swizzled

    const int tid = threadIdx.x;
    const int w = tid >> 6, l = tid & 63;

    // T1: bijective XCD swizzle (nwg % 8 == 0 for both instantiations)
    constexpr int nb  = NCOLS / 128;
    constexpr int nwg = (N_NODES / 128) * nb;
    constexpr int cpx = nwg / 8;
    const int bid = blockIdx.x;
    const int swz = (bid & 7) * cpx + (bid >> 3);
    const int  bn = swz % nb;                    // n fastest -> A-panel L2 reuse
    const long m0 = (long)(swz / nb) * 128;
    const int  n0 = bn * 128;

    // staging: thread covers row (r*32 + trow), 16B granule tg; LDS dest is
    // linear tid*16 per 4KB round; global col pre-swizzled (inverse of read).
    const int trow = tid >> 3;                   // 32 rows per round
    const int tg   = tid & 7;
    const int kes  = ((tg * 16) ^ ((trow & 7) << 4)) >> 1;

    f32x4 acc[4][4];
    #pragma unroll
    for (int i = 0; i < 4; ++i)
        #pragma unroll
        for (int j = 0; j < 4; ++j) acc[i][j] = f32x4{0.f, 0.f, 0.f, 0.f};

    const int wr = w >> 1, wc = w & 1;           // 2x2 wave grid
    const int lr = l & 15, lg = l >> 4;

    for (int k0 = 0; k0 < KTOT; k0 += 64) {
        __syncthreads();
        const bf16* Asrc; long astr; int kofs;
        if (MODE == 2 && k0 >= D_IN) { Asrc = A2; astr = D_H;  kofs = k0 - D_IN; }
        else                         { Asrc = A;  astr = KTOT; kofs = k0; }
        #pragma unroll
        for (int r = 0; r < 4; ++r)              // A: 128 rows, 4 rounds
            gload_lds16(Asrc + (m0 + r * 32 + trow) * astr + kofs + kes,
                        Atile + r * 4096 + tid * 16);
        #pragma unroll
        for (int r = 0; r < 4; ++r)              // B: 128 cols, 4 rounds
            gload_lds16(W + (long)(n0 + r * 32 + trow) * KTOT + k0 + kes,
                        Btile + r * 4096 + tid * 16);
        __syncthreads();   // compiler drains vmcnt before s_barrier

        #pragma unroll
        for (int ks = 0; ks < 2; ++ks) {
            bf16x8 af[4];
            #pragma unroll
            for (int mi = 0; mi < 4; ++mi) {
                int row = wr * 64 + mi * 16 + lr;
                int addr = (row << 7) + ((ks * 64 + lg * 16) ^ ((row & 7) << 4));
                af[mi] = *(const bf16x8*)(Atile + addr);
            }
            #pragma unroll
            for (int ni = 0; ni < 4; ++ni) {
                int row = wc * 64 + ni * 16 + lr;
                int addr = (row << 7) + ((ks * 64 + lg * 16) ^ ((row & 7) << 4));
                bf16x8 bfr = *(const bf16x8*)(Btile + addr);
                #pragma unroll
                for (int mi = 0; mi < 4; ++mi)
                    acc[mi][ni] = __builtin_amdgcn_mfma_f32_16x16x32_bf16(
                        af[mi], bfr, acc[mi][ni], 0, 0, 0);
            }
        }
    }

    // epilogue: C/D layout col = lane&15, row = (lane>>4)*4 + j   [m89 verified]
    #pragma unroll
    for (int mi = 0; mi < 4; ++mi) {
        #pragma unroll
        for (int ni = 0; ni < 4; ++ni) {
            int gc = n0 + wc * 64 + ni * 16 + lr;
            float bv = bias[gc];
            #pragma unroll
            for (int j = 0; j < 4; ++j) {
                long gr = m0 + wr * 64 + mi * 16 + lg * 4 + j;
                float v = acc[mi][ni][j] + bv;
                if (MODE == 1) {
                    float s = 1.f / (1.f + __expf(-v));
                    if (NCOLS == NG1 && n0 < D_H) {          // Z half (block-uniform)
                        Hout[gr * D_H + gc] = s;             // Z staged in f32
                    } else {
                        float ph = (float)A[gr * KTOT + D_IN + (gc - D_H)];
                        Rapp_out[gr * D_H + (gc - D_H)] = (bf16)(s * ph);
                    }
                } else {
                    float ht = 2.f / (1.f + __expf(-2.f * v)) - 1.f;   // tanh
                    long  o  = gr * D_H + gc;
                    float zz = Hout[o];
                    float ph = (float)A[gr * KTOT + D_IN + gc];
                    Hout[o] = zz * ph + (1.f - zz) * ht;
                }
            }
        }
    }
}

// ---------------- fusion: segment_sum(z) | relu(u@Wg+bg) per graph ----------
__global__ __launch_bounds__(256)
void fusion_kernel(const float* __restrict__ z, const float* __restrict__ u,
                   const float* __restrict__ Wg, const float* __restrict__ bg,
                   const int* __restrict__ batch, float* __restrict__ out)
{
    int g = blockIdx.x;
    __shared__ float us[D_U];
    __shared__ int   rng[2];
    int tid = threadIdx.x;
    if (tid < D_U) us[tid] = u[(long)g * D_U + tid];
    if (tid < 2) {
        int target = g + tid;     // lower_bound(batch, target)
        int lo = 0, hi = N_NODES;
        while (lo < hi) { int mid = (lo + hi) >> 1; if (batch[mid] < target) lo = mid + 1; else hi = mid; }
        rng[tid] = lo;
    }
    __syncthreads();
    int start = rng[0], end = rng[1];
    int d0 = tid * 2;
    float s0 = 0.f, s1 = 0.f;
    for (int n = start; n < end; ++n) {
        const float* zp = z + (long)n * D_Z + d0;
        s0 += zp[0]; s1 += zp[1];
    }
    long ob = (long)g * 1024;
    out[ob + d0]     = s0;
    out[ob + d0 + 1] = s1;
    float a0 = bg[d0], a1 = bg[d0 + 1];
    #pragma unroll 8
    for (int k = 0; k < D_U; ++k) {
        float uv = us[k];
        a0 += uv * Wg[k * D_Z + d0];
        a1 += uv * Wg[k * D_Z + d0 + 1];
    }
    out[ob + 512 + d0]     = fmaxf(a0, 0.f);
    out[ob + 512 + d0 + 1] = fmaxf(a1, 0.f);
}

// ---------------------------------------------------------------------------
extern "C" void kernel_launch(void* const* d_in, const int* in_sizes, int n_in,
                              void* d_out, int out_size, void* d_ws, size_t ws_size,
                              hipStream_t stream) {
    (void)in_sizes; (void)n_in; (void)out_size; (void)ws_size;
    const float* z      = (const float*)d_in[0];
    const float* u      = (const float*)d_in[1];
    const float* x      = (const float*)d_in[2];
    const float* prev_h = (const float*)d_in[3];
    // d_in[4] edge_index unused (K=1 ChebConv)
    const int*   batch  = (const int*)d_in[5];
    // d_in[6] batch_size == 4096 (fixed)
    const float* Wxz = (const float*)d_in[7];
    const float* bxz = (const float*)d_in[8];
    const float* Whz = (const float*)d_in[9];
    const float* bhz = (const float*)d_in[10];
    const float* Wxr = (const float*)d_in[11];
    const float* bxr = (const float*)d_in[12];
    const float* Whr = (const float*)d_in[13];
    const float* bhr = (const float*)d_in[14];
    const float* Wxh = (const float*)d_in[15];
    const float* bxh = (const float*)d_in[16];
    const float* Whh = (const float*)d_in[17];
    const float* bhh = (const float*)d_in[18];
    const float* Wg  = (const float*)d_in[19];
    const float* bg  = (const float*)d_in[20];

    char* ws = (char*)d_ws;
    bf16*  WT1   = (bf16*)ws;                                  // 2,621,440 B
    bf16*  WT2   = (bf16*)(ws + 2621440);                      // 1,310,720 B
    float* bias1 = (float*)(ws + 3932160);                     // 4 KB
    float* bias2 = (float*)(ws + 3936256);                     // 2 KB
    bf16*  Rapp  = (bf16*)(ws + 4194304);                      // 134,217,728 B
    bf16*  Abf   = (bf16*)(ws + 4194304 + 134217728);          // 335,544,320 B

    float* outF = (float*)d_out;
    float* Hout = outF + (long)N_GRAPHS * 1024;                // H region (also Z staging)

    hipLaunchKernelGGL(prep_weights, dim3(960), dim3(256), 0, stream,
                       Wxz, Whz, Wxr, Whr, Wxh, Whh,
                       bxz, bhz, bxr, bhr, bxh, bhh,
                       WT1, WT2, bias1, bias2);
    hipLaunchKernelGGL(prep_A, dim3(81920), dim3(256), 0, stream, z, x, prev_h, Abf);
    hipLaunchKernelGGL((gemm_kernel<NG1, 1>), dim3(8192), dim3(256), 0, stream,
                       Abf, (const bf16*)nullptr, WT1, bias1, Hout, Rapp);
    hipLaunchKernelGGL((gemm_kernel<D_H, 2>), dim3(4096), dim3(256), 0, stream,
                       Abf, Rapp, WT2, bias2, Hout, (bf16*)nullptr);
    hipLaunchKernelGGL(fusion_kernel, dim3(N_GRAPHS), dim3(256), 0, stream,
                       z, u, Wg, bg, batch, outF);
}